// Round 4
// baseline (125.779 us; speedup 1.0000x reference)
//
#include <hip/hip_runtime.h>
#include <math.h>

#define TWO_PI_F 6.283185307179586f
#define ROWS 1024          // rows per tile
#define BLK  256

// Kernel A: per-group rotation matrices, padded to 12 floats/group
// (rows at float4 offsets 0,1,2). R = I + sin*K + (1-cos)*K^2; identity if
// apply_rand >= 0.5.
__global__ void compute_R_kernel(const float* __restrict__ axis,
                                 const float* __restrict__ angle,
                                 const float* __restrict__ apply_rand,
                                 float* __restrict__ R, int G) {
    int g = blockIdx.x * blockDim.x + threadIdx.x;
    if (g >= G) return;
    float a = axis[3 * g + 0];
    float b = axis[3 * g + 1];
    float c = axis[3 * g + 2];
    float inv = rsqrtf(a * a + b * b + c * c);
    a *= inv; b *= inv; c *= inv;
    float th = angle[g] * TWO_PI_F;
    float s, co;
    sincosf(th, &s, &co);
    float omc = 1.0f - co;

    float r00 = 1.0f - omc * (b * b + c * c);
    float r01 = -s * c + omc * (a * b);
    float r02 =  s * b + omc * (a * c);
    float r10 =  s * c + omc * (a * b);
    float r11 = 1.0f - omc * (a * a + c * c);
    float r12 = -s * a + omc * (b * c);
    float r20 = -s * b + omc * (a * c);
    float r21 =  s * a + omc * (b * c);
    float r22 = 1.0f - omc * (a * a + b * b);

    if (!(apply_rand[g] < 0.5f)) {
        r00 = 1.0f; r01 = 0.0f; r02 = 0.0f;
        r10 = 0.0f; r11 = 1.0f; r12 = 0.0f;
        r20 = 0.0f; r21 = 0.0f; r22 = 1.0f;
    }
    float4* Rg = reinterpret_cast<float4*>(R + 12 * (size_t)g);
    Rg[0] = make_float4(r00, r01, r02, 0.0f);
    Rg[1] = make_float4(r10, r11, r12, 0.0f);
    Rg[2] = make_float4(r20, r21, r22, 0.0f);
}

// Fused persistent kernel: grid-strides over a unified tile list covering
// edges, nodes, then y. Per tile: 1024 rows = 768 float4 = 12 KB LDS.
// Double-buffered: prefetch tile t+stride into registers while computing
// tile t; raw s_barrier (no vmcnt drain) keeps the prefetch in flight.
__global__ __launch_bounds__(BLK, 6) void apply_all(
        const float* __restrict__ xv, const int* __restrict__ nbatch,
        float* __restrict__ xo, int N, int TN,
        const float* __restrict__ ev, const int* __restrict__ ebatch,
        float* __restrict__ eo, int E, int TE,
        const float* __restrict__ yv, float* __restrict__ yo, int G, int TG,
        const float* __restrict__ R) {
    __shared__ float buf[2][ROWS * 3];
    const int tid = threadIdx.x;
    const int TT = TE + TN + TG;
    const int stride = gridDim.x;

    auto resolve = [&](int t, const float*& v, const int*& bt, float*& o,
                       size_t& rb, int& rows) {
        if (t < TE) {
            v = ev; bt = ebatch; o = eo;
            rb = (size_t)t * ROWS;
            int rem = E - (int)rb; rows = rem < ROWS ? rem : ROWS;
        } else if (t < TE + TN) {
            int u = t - TE;
            v = xv; bt = nbatch; o = xo;
            rb = (size_t)u * ROWS;
            int rem = N - (int)rb; rows = rem < ROWS ? rem : ROWS;
        } else {
            int u = t - TE - TN;
            v = yv; bt = nullptr; o = yo;
            rb = (size_t)u * ROWS;
            int rem = G - (int)rb; rows = rem < ROWS ? rem : ROWS;
        }
    };

    int t = blockIdx.x;
    if (t >= TT) return;

    const float* v; const int* bt; float* o; size_t rb; int rows;
    resolve(t, v, bt, o, rb, rows);

    float4 pr0 = make_float4(0, 0, 0, 0);
    float4 pr1 = pr0, pr2 = pr0;
    float prT = 0.f;
    {   // prologue: load tile t
        const float4* src = reinterpret_cast<const float4*>(v + rb * 3);
        int f4 = (rows * 3) >> 2;
        if (tid < f4)       pr0 = src[tid];
        if (tid + 256 < f4) pr1 = src[tid + 256];
        if (tid + 512 < f4) pr2 = src[tid + 512];
        int tf = (rows * 3) & 3;
        if (tf && tid < tf) prT = v[rb * 3 + ((size_t)f4 << 2) + tid];
    }
    {   // stage tile t into buf[0]
        float4* b4 = reinterpret_cast<float4*>(buf[0]);
        int f4 = (rows * 3) >> 2;
        if (tid < f4)       b4[tid] = pr0;
        if (tid + 256 < f4) b4[tid + 256] = pr1;
        if (tid + 512 < f4) b4[tid + 512] = pr2;
        int tf = (rows * 3) & 3;
        if (tf && tid < tf) buf[0][(f4 << 2) + tid] = prT;
    }

    int cur = 0;
    while (true) {
        const int*   btC   = bt;
        float*       oC    = o;
        size_t       rbC   = rb;
        int          rowsC = rows;

        int  tn = t + stride;
        bool hasNext = tn < TT;
        if (hasNext) {
            // issue next tile's global loads NOW; they stay in flight
            // across the barriers below (counted vmcnt, no drain).
            resolve(tn, v, bt, o, rb, rows);
            const float4* src = reinterpret_cast<const float4*>(v + rb * 3);
            int f4 = (rows * 3) >> 2;
            pr0 = make_float4(0, 0, 0, 0); pr1 = pr0; pr2 = pr0; prT = 0.f;
            if (tid < f4)       pr0 = src[tid];
            if (tid + 256 < f4) pr1 = src[tid + 256];
            if (tid + 512 < f4) pr2 = src[tid + 512];
            int tf = (rows * 3) & 3;
            if (tf && tid < tf) prT = v[rb * 3 + ((size_t)f4 << 2) + tid];
        }

        asm volatile("s_waitcnt lgkmcnt(0)" ::: "memory");
        __builtin_amdgcn_s_barrier();           // B1: buf[cur] fully staged

        // ---- phase 2: rotate 4 rows/thread in place ----
        {
            float4* b4 = reinterpret_cast<float4*>(buf[cur]);
            int nRow4 = rowsC >> 2;
            if (tid < nRow4) {
                float4 p0 = b4[3 * tid + 0];
                float4 p1 = b4[3 * tid + 1];
                float4 p2 = b4[3 * tid + 2];
                float rowsv[4][3] = {
                    {p0.x, p0.y, p0.z},
                    {p0.w, p1.x, p1.y},
                    {p1.z, p1.w, p2.x},
                    {p2.y, p2.z, p2.w}};
                int gs[4];
                if (btC) {
                    int4 bi = *(reinterpret_cast<const int4*>(btC + rbC) + tid);
                    gs[0] = bi.x; gs[1] = bi.y; gs[2] = bi.z; gs[3] = bi.w;
                } else {
                    int base = (int)rbC + 4 * tid;
                    gs[0] = base; gs[1] = base + 1; gs[2] = base + 2; gs[3] = base + 3;
                }
                float oo[12];
#pragma unroll
                for (int r = 0; r < 4; ++r) {
                    const float4* Rg = reinterpret_cast<const float4*>(R + 12 * (size_t)gs[r]);
                    float4 R0 = Rg[0];
                    float4 R1 = Rg[1];
                    float4 R2 = Rg[2];
                    float v0 = rowsv[r][0], v1 = rowsv[r][1], v2 = rowsv[r][2];
                    oo[3 * r + 0] = R0.x * v0 + R0.y * v1 + R0.z * v2;
                    oo[3 * r + 1] = R1.x * v0 + R1.y * v1 + R1.z * v2;
                    oo[3 * r + 2] = R2.x * v0 + R2.y * v1 + R2.z * v2;
                }
                b4[3 * tid + 0] = make_float4(oo[0], oo[1], oo[2], oo[3]);
                b4[3 * tid + 1] = make_float4(oo[4], oo[5], oo[6], oo[7]);
                b4[3 * tid + 2] = make_float4(oo[8], oo[9], oo[10], oo[11]);
            } else if (tid == nRow4 && (rowsC & 3)) {
                float* bf = buf[cur];
                for (int r = nRow4 * 4; r < rowsC; ++r) {
                    size_t row = rbC + r;
                    int g = btC ? btC[row] : (int)row;
                    const float* Rg = R + 12 * (size_t)g;
                    float v0 = bf[3 * r + 0], v1 = bf[3 * r + 1], v2 = bf[3 * r + 2];
                    float t0 = Rg[0] * v0 + Rg[1] * v1 + Rg[2]  * v2;
                    float t1 = Rg[4] * v0 + Rg[5] * v1 + Rg[6]  * v2;
                    float t2 = Rg[8] * v0 + Rg[9] * v1 + Rg[10] * v2;
                    bf[3 * r + 0] = t0; bf[3 * r + 1] = t1; bf[3 * r + 2] = t2;
                }
            }
        }

        asm volatile("s_waitcnt lgkmcnt(0)" ::: "memory");
        __builtin_amdgcn_s_barrier();           // B2: rotated data visible

        if (hasNext) {
            // stage next tile into the other buffer (compiler inserts the
            // counted vmcnt wait for the prefetch registers here).
            float4* b4 = reinterpret_cast<float4*>(buf[cur ^ 1]);
            int f4 = (rows * 3) >> 2;
            if (tid < f4)       b4[tid] = pr0;
            if (tid + 256 < f4) b4[tid + 256] = pr1;
            if (tid + 512 < f4) b4[tid + 512] = pr2;
            int tf = (rows * 3) & 3;
            if (tf && tid < tf) buf[cur ^ 1][(f4 << 2) + tid] = prT;
        }

        // ---- phase 3: coalesced writeout of buf[cur] ----
        {
            const float4* b4 = reinterpret_cast<const float4*>(buf[cur]);
            float4* dst = reinterpret_cast<float4*>(oC + rbC * 3);
            int f4 = (rowsC * 3) >> 2;
            if (tid < f4)       dst[tid] = b4[tid];
            if (tid + 256 < f4) dst[tid + 256] = b4[tid + 256];
            if (tid + 512 < f4) dst[tid + 512] = b4[tid + 512];
            int tf = (rowsC * 3) & 3;
            if (tf && tid < tf) oC[rbC * 3 + ((size_t)f4 << 2) + tid] = buf[cur][(f4 << 2) + tid];
        }

        if (!hasNext) break;
        cur ^= 1;
        t = tn;
    }
}

extern "C" void kernel_launch(void* const* d_in, const int* in_sizes, int n_in,
                              void* d_out, int out_size, void* d_ws, size_t ws_size,
                              hipStream_t stream) {
    const float* x          = (const float*)d_in[0];
    const float* edge_attr  = (const float*)d_in[1];
    const float* y          = (const float*)d_in[2];
    const int*   node_batch = (const int*)d_in[3];
    const int*   edge_batch = (const int*)d_in[4];
    const float* axis       = (const float*)d_in[5];
    const float* angle      = (const float*)d_in[6];
    const float* apply_rand = (const float*)d_in[7];

    const int N = in_sizes[3];
    const int E = in_sizes[4];
    const int G = in_sizes[6];

    float* R = (float*)d_ws;        // G*12 floats = 384 KB
    float* x_out = (float*)d_out;
    float* e_out = x_out + 3 * (size_t)N;
    float* y_out = e_out + 3 * (size_t)E;

    compute_R_kernel<<<(G + BLK - 1) / BLK, BLK, 0, stream>>>(
        axis, angle, apply_rand, R, G);

    int TN = (N + ROWS - 1) / ROWS;
    int TE = (E + ROWS - 1) / ROWS;
    int TG = (G + ROWS - 1) / ROWS;
    int TT = TN + TE + TG;
    int grid = TT < 1536 ? TT : 1536;   // 6 blocks/CU * 256 CUs

    apply_all<<<grid, BLK, 0, stream>>>(
        x, node_batch, x_out, N, TN,
        edge_attr, edge_batch, e_out, E, TE,
        y, y_out, G, TG, R);
}

// Round 5
// 123.820 us; speedup vs baseline: 1.0158x; 1.0158x over previous
//
#include <hip/hip_runtime.h>
#include <math.h>

#define TWO_PI_F 6.283185307179586f
#define ROWS 1024          // rows per tile (12 KB LDS)
#define BLK  256

// Kernel A: per-group rotation matrices, padded to 12 floats/group
// (rows at float4 offsets 0,1,2). R = I + sin*K + (1-cos)*K^2; identity if
// apply_rand >= 0.5.
__global__ void compute_R_kernel(const float* __restrict__ axis,
                                 const float* __restrict__ angle,
                                 const float* __restrict__ apply_rand,
                                 float* __restrict__ R, int G) {
    int g = blockIdx.x * blockDim.x + threadIdx.x;
    if (g >= G) return;
    float a = axis[3 * g + 0];
    float b = axis[3 * g + 1];
    float c = axis[3 * g + 2];
    float inv = rsqrtf(a * a + b * b + c * c);
    a *= inv; b *= inv; c *= inv;
    float th = angle[g] * TWO_PI_F;
    float s, co;
    sincosf(th, &s, &co);
    float omc = 1.0f - co;

    float r00 = 1.0f - omc * (b * b + c * c);
    float r01 = -s * c + omc * (a * b);
    float r02 =  s * b + omc * (a * c);
    float r10 =  s * c + omc * (a * b);
    float r11 = 1.0f - omc * (a * a + c * c);
    float r12 = -s * a + omc * (b * c);
    float r20 = -s * b + omc * (a * c);
    float r21 =  s * a + omc * (b * c);
    float r22 = 1.0f - omc * (a * a + b * b);

    if (!(apply_rand[g] < 0.5f)) {
        r00 = 1.0f; r01 = 0.0f; r02 = 0.0f;
        r10 = 0.0f; r11 = 1.0f; r12 = 0.0f;
        r20 = 0.0f; r21 = 0.0f; r22 = 1.0f;
    }
    float4* Rg = reinterpret_cast<float4*>(R + 12 * (size_t)g);
    Rg[0] = make_float4(r00, r01, r02, 0.0f);
    Rg[1] = make_float4(r10, r11, r12, 0.0f);
    Rg[2] = make_float4(r20, r21, r22, 0.0f);
}

// Fused non-persistent kernel: one 1024-row tile per block over a unified
// tile list (edges, then nodes, then y). 12 KB LDS -> 8 blocks/CU; cross-
// block TLP hides the per-block load->compute->store chain.
__global__ __launch_bounds__(BLK, 8) void apply_fused(
        const float* __restrict__ ev, const int* __restrict__ ebatch,
        float* __restrict__ eo, int E, int TE,
        const float* __restrict__ xv, const int* __restrict__ nbatch,
        float* __restrict__ xo, int N, int TN,
        const float* __restrict__ yv, float* __restrict__ yo, int G,
        const float* __restrict__ R) {
    __shared__ float buf[ROWS * 3];
    float4* buf4 = reinterpret_cast<float4*>(buf);
    const int tid = threadIdx.x;
    const int t = blockIdx.x;

    const float* v; const int* bt; float* o; size_t rb; int rows;
    if (t < TE) {
        v = ev; bt = ebatch; o = eo; rb = (size_t)t * ROWS;
        int rem = E - (int)rb; rows = rem < ROWS ? rem : ROWS;
    } else if (t < TE + TN) {
        int u = t - TE;
        v = xv; bt = nbatch; o = xo; rb = (size_t)u * ROWS;
        int rem = N - (int)rb; rows = rem < ROWS ? rem : ROWS;
    } else {
        int u = t - TE - TN;
        v = yv; bt = nullptr; o = yo; rb = (size_t)u * ROWS;
        int rem = G - (int)rb; rows = rem < ROWS ? rem : ROWS;
    }

    const int floatsHere = rows * 3;
    const int f4Here = floatsHere >> 2;
    const int tailFloats = floatsHere & 3;
    const int nRow4 = rows >> 2;

    // ---- batch prefetch: issue BEFORE staging so it's off the critical
    // path between the barriers (it was a dependent load there in R3). ----
    int4 bi = make_int4(0, 0, 0, 0);
    if (tid < nRow4) {
        if (bt) {
            bi = *(reinterpret_cast<const int4*>(bt + rb) + tid);
        } else {
            int base = (int)rb + 4 * tid;
            bi = make_int4(base, base + 1, base + 2, base + 3);
        }
    }

    // ---- phase 1: coalesced global -> LDS ----
    {
        const float4* src = reinterpret_cast<const float4*>(v + rb * 3);
        if (tid < f4Here)       buf4[tid]       = src[tid];
        if (tid + 256 < f4Here) buf4[tid + 256] = src[tid + 256];
        if (tid + 512 < f4Here) buf4[tid + 512] = src[tid + 512];
        if (tailFloats && tid < tailFloats) {
            int fi = (f4Here << 2) + tid;
            buf[fi] = v[rb * 3 + fi];
        }
    }
    __syncthreads();

    // ---- phase 2: rotate 4 rows per thread, in place ----
    if (tid < nRow4) {
        float4 p0 = buf4[3 * tid + 0];
        float4 p1 = buf4[3 * tid + 1];
        float4 p2 = buf4[3 * tid + 2];
        float rowsv[4][3] = {
            {p0.x, p0.y, p0.z},
            {p0.w, p1.x, p1.y},
            {p1.z, p1.w, p2.x},
            {p2.y, p2.z, p2.w}};
        int gs[4] = {bi.x, bi.y, bi.z, bi.w};
        float oo[12];
#pragma unroll
        for (int r = 0; r < 4; ++r) {
            const float4* Rg = reinterpret_cast<const float4*>(R + 12 * (size_t)gs[r]);
            float4 R0 = Rg[0];
            float4 R1 = Rg[1];
            float4 R2 = Rg[2];
            float v0 = rowsv[r][0], v1 = rowsv[r][1], v2 = rowsv[r][2];
            oo[3 * r + 0] = R0.x * v0 + R0.y * v1 + R0.z * v2;
            oo[3 * r + 1] = R1.x * v0 + R1.y * v1 + R1.z * v2;
            oo[3 * r + 2] = R2.x * v0 + R2.y * v1 + R2.z * v2;
        }
        buf4[3 * tid + 0] = make_float4(oo[0], oo[1], oo[2], oo[3]);
        buf4[3 * tid + 1] = make_float4(oo[4], oo[5], oo[6], oo[7]);
        buf4[3 * tid + 2] = make_float4(oo[8], oo[9], oo[10], oo[11]);
    } else if (tid == nRow4 && (rows & 3)) {
        // scalar tail rows — not hit for these sizes, kept for safety
        for (int r = nRow4 * 4; r < rows; ++r) {
            size_t row = rb + r;
            int g = bt ? bt[row] : (int)row;
            const float* Rg = R + 12 * (size_t)g;
            float v0 = buf[3 * r + 0], v1 = buf[3 * r + 1], v2 = buf[3 * r + 2];
            float t0 = Rg[0] * v0 + Rg[1] * v1 + Rg[2]  * v2;
            float t1 = Rg[4] * v0 + Rg[5] * v1 + Rg[6]  * v2;
            float t2 = Rg[8] * v0 + Rg[9] * v1 + Rg[10] * v2;
            buf[3 * r + 0] = t0; buf[3 * r + 1] = t1; buf[3 * r + 2] = t2;
        }
    }
    __syncthreads();

    // ---- phase 3: coalesced LDS -> global ----
    {
        float4* dst = reinterpret_cast<float4*>(o + rb * 3);
        if (tid < f4Here)       dst[tid]       = buf4[tid];
        if (tid + 256 < f4Here) dst[tid + 256] = buf4[tid + 256];
        if (tid + 512 < f4Here) dst[tid + 512] = buf4[tid + 512];
        if (tailFloats && tid < tailFloats) {
            int fi = (f4Here << 2) + tid;
            o[rb * 3 + fi] = buf[fi];
        }
    }
}

extern "C" void kernel_launch(void* const* d_in, const int* in_sizes, int n_in,
                              void* d_out, int out_size, void* d_ws, size_t ws_size,
                              hipStream_t stream) {
    const float* x          = (const float*)d_in[0];
    const float* edge_attr  = (const float*)d_in[1];
    const float* y          = (const float*)d_in[2];
    const int*   node_batch = (const int*)d_in[3];
    const int*   edge_batch = (const int*)d_in[4];
    const float* axis       = (const float*)d_in[5];
    const float* angle      = (const float*)d_in[6];
    const float* apply_rand = (const float*)d_in[7];

    const int N = in_sizes[3];
    const int E = in_sizes[4];
    const int G = in_sizes[6];

    float* R = (float*)d_ws;        // G*12 floats = 384 KB
    float* x_out = (float*)d_out;
    float* e_out = x_out + 3 * (size_t)N;
    float* y_out = e_out + 3 * (size_t)E;

    compute_R_kernel<<<(G + BLK - 1) / BLK, BLK, 0, stream>>>(
        axis, angle, apply_rand, R, G);

    int TE = (E + ROWS - 1) / ROWS;
    int TN = (N + ROWS - 1) / ROWS;
    int TG = (G + ROWS - 1) / ROWS;
    int TT = TE + TN + TG;

    apply_fused<<<TT, BLK, 0, stream>>>(
        edge_attr, edge_batch, e_out, E, TE,
        x, node_batch, x_out, N, TN,
        y, y_out, G,
        R);
}

// Round 7
// 102.285 us; speedup vs baseline: 1.2297x; 1.2105x over previous
//
#include <hip/hip_runtime.h>
#include <math.h>

#define TWO_PI_F 6.283185307179586f
#define ROWS 1024          // rows per tile (12 KB LDS)
#define BLK  256

typedef float f32x4 __attribute__((ext_vector_type(4)));

// Kernel A: per-group rotation matrices, padded to 12 floats/group
// (rows at float4 offsets 0,1,2). R = I + sin*K + (1-cos)*K^2; identity if
// apply_rand >= 0.5.
__global__ void compute_R_kernel(const float* __restrict__ axis,
                                 const float* __restrict__ angle,
                                 const float* __restrict__ apply_rand,
                                 float* __restrict__ R, int G) {
    int g = blockIdx.x * blockDim.x + threadIdx.x;
    if (g >= G) return;
    float a = axis[3 * g + 0];
    float b = axis[3 * g + 1];
    float c = axis[3 * g + 2];
    float inv = rsqrtf(a * a + b * b + c * c);
    a *= inv; b *= inv; c *= inv;
    float th = angle[g] * TWO_PI_F;
    float s, co;
    sincosf(th, &s, &co);
    float omc = 1.0f - co;

    float r00 = 1.0f - omc * (b * b + c * c);
    float r01 = -s * c + omc * (a * b);
    float r02 =  s * b + omc * (a * c);
    float r10 =  s * c + omc * (a * b);
    float r11 = 1.0f - omc * (a * a + c * c);
    float r12 = -s * a + omc * (b * c);
    float r20 = -s * b + omc * (a * c);
    float r21 =  s * a + omc * (b * c);
    float r22 = 1.0f - omc * (a * a + b * b);

    if (!(apply_rand[g] < 0.5f)) {
        r00 = 1.0f; r01 = 0.0f; r02 = 0.0f;
        r10 = 0.0f; r11 = 1.0f; r12 = 0.0f;
        r20 = 0.0f; r21 = 0.0f; r22 = 1.0f;
    }
    float4* Rg = reinterpret_cast<float4*>(R + 12 * (size_t)g);
    Rg[0] = make_float4(r00, r01, r02, 0.0f);
    Rg[1] = make_float4(r10, r11, r12, 0.0f);
    Rg[2] = make_float4(r20, r21, r22, 0.0f);
}

// Kernel B (LDS-staged, R3 structure): block of 256 threads owns 1024 rows
// (3072 floats = 768 float4 = 12 KB LDS). Global I/O fully lane-contiguous
// float4; the stride-12-float AoS shuffle happens in LDS. Output stores are
// NON-TEMPORAL: outputs are write-once, keep them from evicting the input
// set (288 MB vs 256 MB L3) across timed replays.
template <bool HAS_BATCH>
__global__ __launch_bounds__(BLK) void apply_rot_lds(
        const float* __restrict__ v,
        const int* __restrict__ batch,
        const float* __restrict__ R,
        float* __restrict__ out, int n) {
    __shared__ float buf[ROWS * 3];
    float4* buf4 = reinterpret_cast<float4*>(buf);

    const int tid = threadIdx.x;
    const size_t rowBase = (size_t)blockIdx.x * ROWS;
    int rows = n - (int)rowBase;
    if (rows > ROWS) rows = ROWS;
    const int floatsHere = rows * 3;
    const int f4Here = floatsHere >> 2;
    const int tailFloats = floatsHere & 3;
    const int nRow4 = rows >> 2;

    // ---- batch prefetch: issued before staging, off the critical path ----
    int4 bi = make_int4(0, 0, 0, 0);
    if (tid < nRow4) {
        if (HAS_BATCH) {
            bi = *(reinterpret_cast<const int4*>(batch + rowBase) + tid);
        } else {
            int base = (int)rowBase + 4 * tid;
            bi = make_int4(base, base + 1, base + 2, base + 3);
        }
    }

    // ---- phase 1: coalesced global -> LDS ----
    {
        const float4* src = reinterpret_cast<const float4*>(v + rowBase * 3);
        if (tid < f4Here)       buf4[tid]       = src[tid];
        if (tid + 256 < f4Here) buf4[tid + 256] = src[tid + 256];
        if (tid + 512 < f4Here) buf4[tid + 512] = src[tid + 512];
        if (tailFloats && tid < tailFloats) {
            int fi = (f4Here << 2) + tid;
            buf[fi] = v[rowBase * 3 + fi];
        }
    }
    __syncthreads();

    // ---- phase 2: rotate 4 rows per thread, in place ----
    if (tid < nRow4) {
        float4 p0 = buf4[3 * tid + 0];
        float4 p1 = buf4[3 * tid + 1];
        float4 p2 = buf4[3 * tid + 2];
        float rowsv[4][3] = {
            {p0.x, p0.y, p0.z},
            {p0.w, p1.x, p1.y},
            {p1.z, p1.w, p2.x},
            {p2.y, p2.z, p2.w}};
        int gs[4] = {bi.x, bi.y, bi.z, bi.w};
        float oo[12];
#pragma unroll
        for (int r = 0; r < 4; ++r) {
            const float4* Rg = reinterpret_cast<const float4*>(R + 12 * (size_t)gs[r]);
            float4 R0 = Rg[0];
            float4 R1 = Rg[1];
            float4 R2 = Rg[2];
            float v0 = rowsv[r][0], v1 = rowsv[r][1], v2 = rowsv[r][2];
            oo[3 * r + 0] = R0.x * v0 + R0.y * v1 + R0.z * v2;
            oo[3 * r + 1] = R1.x * v0 + R1.y * v1 + R1.z * v2;
            oo[3 * r + 2] = R2.x * v0 + R2.y * v1 + R2.z * v2;
        }
        buf4[3 * tid + 0] = make_float4(oo[0], oo[1], oo[2], oo[3]);
        buf4[3 * tid + 1] = make_float4(oo[4], oo[5], oo[6], oo[7]);
        buf4[3 * tid + 2] = make_float4(oo[8], oo[9], oo[10], oo[11]);
    } else if (tid == nRow4 && (rows & 3)) {
        // scalar tail rows — not hit for these sizes, kept for safety
        for (int r = nRow4 * 4; r < rows; ++r) {
            size_t row = rowBase + r;
            int g = HAS_BATCH ? batch[row] : (int)row;
            const float* Rg = R + 12 * (size_t)g;
            float v0 = buf[3 * r + 0], v1 = buf[3 * r + 1], v2 = buf[3 * r + 2];
            float t0 = Rg[0] * v0 + Rg[1] * v1 + Rg[2]  * v2;
            float t1 = Rg[4] * v0 + Rg[5] * v1 + Rg[6]  * v2;
            float t2 = Rg[8] * v0 + Rg[9] * v1 + Rg[10] * v2;
            buf[3 * r + 0] = t0; buf[3 * r + 1] = t1; buf[3 * r + 2] = t2;
        }
    }
    __syncthreads();

    // ---- phase 3: coalesced LDS -> global, non-temporal (ext-vector type;
    // HIP's float4 class is rejected by the builtin) ----
    {
        const f32x4* b4 = reinterpret_cast<const f32x4*>(buf);
        f32x4* dst = reinterpret_cast<f32x4*>(out + rowBase * 3);
        if (tid < f4Here) {
            f32x4 val = b4[tid];
            __builtin_nontemporal_store(val, &dst[tid]);
        }
        if (tid + 256 < f4Here) {
            f32x4 val = b4[tid + 256];
            __builtin_nontemporal_store(val, &dst[tid + 256]);
        }
        if (tid + 512 < f4Here) {
            f32x4 val = b4[tid + 512];
            __builtin_nontemporal_store(val, &dst[tid + 512]);
        }
        if (tailFloats && tid < tailFloats) {
            int fi = (f4Here << 2) + tid;
            __builtin_nontemporal_store(buf[fi], &out[rowBase * 3 + fi]);
        }
    }
}

extern "C" void kernel_launch(void* const* d_in, const int* in_sizes, int n_in,
                              void* d_out, int out_size, void* d_ws, size_t ws_size,
                              hipStream_t stream) {
    const float* x          = (const float*)d_in[0];
    const float* edge_attr  = (const float*)d_in[1];
    const float* y          = (const float*)d_in[2];
    const int*   node_batch = (const int*)d_in[3];
    const int*   edge_batch = (const int*)d_in[4];
    const float* axis       = (const float*)d_in[5];
    const float* angle      = (const float*)d_in[6];
    const float* apply_rand = (const float*)d_in[7];

    const int N = in_sizes[3];
    const int E = in_sizes[4];
    const int G = in_sizes[6];

    float* R = (float*)d_ws;        // G*12 floats = 384 KB
    float* x_out = (float*)d_out;
    float* e_out = x_out + 3 * (size_t)N;
    float* y_out = e_out + 3 * (size_t)E;

    compute_R_kernel<<<(G + BLK - 1) / BLK, BLK, 0, stream>>>(
        axis, angle, apply_rand, R, G);

    int nbN = (N + ROWS - 1) / ROWS;
    int nbE = (E + ROWS - 1) / ROWS;
    int nbG = (G + ROWS - 1) / ROWS;

    apply_rot_lds<true><<<nbE, BLK, 0, stream>>>(edge_attr, edge_batch, R, e_out, E);
    apply_rot_lds<true><<<nbN, BLK, 0, stream>>>(x, node_batch, R, x_out, N);
    apply_rot_lds<false><<<nbG, BLK, 0, stream>>>(y, nullptr, R, y_out, G);
}

// Round 8
// 101.362 us; speedup vs baseline: 1.2409x; 1.0091x over previous
//
#include <hip/hip_runtime.h>
#include <math.h>

#define TWO_PI_F 6.283185307179586f
#define ROWS 1024          // rows per tile (12 KB LDS per buffer)
#define BLK  256

typedef float f32x4 __attribute__((ext_vector_type(4)));

// Kernel A: per-group rotation matrices, padded to 12 floats/group
// (rows at float4 offsets 0,1,2). R = I + sin*K + (1-cos)*K^2; identity if
// apply_rand >= 0.5.
__global__ void compute_R_kernel(const float* __restrict__ axis,
                                 const float* __restrict__ angle,
                                 const float* __restrict__ apply_rand,
                                 float* __restrict__ R, int G) {
    int g = blockIdx.x * blockDim.x + threadIdx.x;
    if (g >= G) return;
    float a = axis[3 * g + 0];
    float b = axis[3 * g + 1];
    float c = axis[3 * g + 2];
    float inv = rsqrtf(a * a + b * b + c * c);
    a *= inv; b *= inv; c *= inv;
    float th = angle[g] * TWO_PI_F;
    float s, co;
    sincosf(th, &s, &co);
    float omc = 1.0f - co;

    float r00 = 1.0f - omc * (b * b + c * c);
    float r01 = -s * c + omc * (a * b);
    float r02 =  s * b + omc * (a * c);
    float r10 =  s * c + omc * (a * b);
    float r11 = 1.0f - omc * (a * a + c * c);
    float r12 = -s * a + omc * (b * c);
    float r20 = -s * b + omc * (a * c);
    float r21 =  s * a + omc * (b * c);
    float r22 = 1.0f - omc * (a * a + b * b);

    if (!(apply_rand[g] < 0.5f)) {
        r00 = 1.0f; r01 = 0.0f; r02 = 0.0f;
        r10 = 0.0f; r11 = 1.0f; r12 = 0.0f;
        r20 = 0.0f; r21 = 0.0f; r22 = 1.0f;
    }
    float4* Rg = reinterpret_cast<float4*>(R + 12 * (size_t)g);
    Rg[0] = make_float4(r00, r01, r02, 0.0f);
    Rg[1] = make_float4(r10, r11, r12, 0.0f);
    Rg[2] = make_float4(r20, r21, r22, 0.0f);
}

// Rotate the rows staged in bufLds (rows block-uniform), 4 rows/thread,
// in place. bi holds the 4 batch indices for this thread's rows.
template <bool HAS_BATCH>
__device__ __forceinline__ void rotate_tile(float* bufLds, int4 bi,
                                            const float* __restrict__ R,
                                            const int* __restrict__ batch,
                                            size_t rowBase, int rows, int tid) {
    float4* buf4 = reinterpret_cast<float4*>(bufLds);
    const int nRow4 = rows >> 2;
    if (tid < nRow4) {
        float4 p0 = buf4[3 * tid + 0];
        float4 p1 = buf4[3 * tid + 1];
        float4 p2 = buf4[3 * tid + 2];
        float rowsv[4][3] = {
            {p0.x, p0.y, p0.z},
            {p0.w, p1.x, p1.y},
            {p1.z, p1.w, p2.x},
            {p2.y, p2.z, p2.w}};
        int gs[4] = {bi.x, bi.y, bi.z, bi.w};
        float oo[12];
#pragma unroll
        for (int r = 0; r < 4; ++r) {
            const float4* Rg = reinterpret_cast<const float4*>(R + 12 * (size_t)gs[r]);
            float4 R0 = Rg[0];
            float4 R1 = Rg[1];
            float4 R2 = Rg[2];
            float v0 = rowsv[r][0], v1 = rowsv[r][1], v2 = rowsv[r][2];
            oo[3 * r + 0] = R0.x * v0 + R0.y * v1 + R0.z * v2;
            oo[3 * r + 1] = R1.x * v0 + R1.y * v1 + R1.z * v2;
            oo[3 * r + 2] = R2.x * v0 + R2.y * v1 + R2.z * v2;
        }
        buf4[3 * tid + 0] = make_float4(oo[0], oo[1], oo[2], oo[3]);
        buf4[3 * tid + 1] = make_float4(oo[4], oo[5], oo[6], oo[7]);
        buf4[3 * tid + 2] = make_float4(oo[8], oo[9], oo[10], oo[11]);
    } else if (tid == nRow4 && (rows & 3)) {
        // scalar tail rows — not hit for these sizes, kept for safety
        for (int r = nRow4 * 4; r < rows; ++r) {
            size_t row = rowBase + r;
            int g = HAS_BATCH ? batch[row] : (int)row;
            const float* Rg = R + 12 * (size_t)g;
            float v0 = bufLds[3 * r + 0], v1 = bufLds[3 * r + 1], v2 = bufLds[3 * r + 2];
            float t0 = Rg[0] * v0 + Rg[1] * v1 + Rg[2]  * v2;
            float t1 = Rg[4] * v0 + Rg[5] * v1 + Rg[6]  * v2;
            float t2 = Rg[8] * v0 + Rg[9] * v1 + Rg[10] * v2;
            bufLds[3 * r + 0] = t0; bufLds[3 * r + 1] = t1; bufLds[3 * r + 2] = t2;
        }
    }
}

// NT store of a tile from LDS to global.
__device__ __forceinline__ void store_tile_nt(const float* bufLds,
                                              float* __restrict__ out,
                                              size_t rowBase, int rows, int tid) {
    const int floatsHere = rows * 3;
    const int f4Here = floatsHere >> 2;
    const int tailFloats = floatsHere & 3;
    const f32x4* b4 = reinterpret_cast<const f32x4*>(bufLds);
    f32x4* dst = reinterpret_cast<f32x4*>(out + rowBase * 3);
    if (tid < f4Here) {
        f32x4 val = b4[tid];
        __builtin_nontemporal_store(val, &dst[tid]);
    }
    if (tid + 256 < f4Here) {
        f32x4 val = b4[tid + 256];
        __builtin_nontemporal_store(val, &dst[tid + 256]);
    }
    if (tid + 512 < f4Here) {
        f32x4 val = b4[tid + 512];
        __builtin_nontemporal_store(val, &dst[tid + 512]);
    }
    if (tailFloats && tid < tailFloats) {
        int fi = (f4Here << 2) + tid;
        __builtin_nontemporal_store(bufLds[fi], &out[rowBase * 3 + fi]);
    }
}

// Kernel B (2-tile pipelined): each block owns TWO adjacent 1024-row tiles.
// ALL global loads (both tiles' data + batch indices) are issued back-to-back
// at kernel start — tile 1's HBM latency hides completely behind tile 0's
// compute+store. LDS double buffer (24 KB). Output stores non-temporal.
template <bool HAS_BATCH>
__global__ __launch_bounds__(BLK) void apply_rot_lds2(
        const float* __restrict__ v,
        const int* __restrict__ batch,
        const float* __restrict__ R,
        float* __restrict__ out, int n) {
    __shared__ float buf[2][ROWS * 3];
    const int tid = threadIdx.x;

    size_t rb0 = (size_t)(blockIdx.x * 2) * ROWS;
    size_t rb1 = rb0 + ROWS;
    int rows0 = n - (int)rb0; rows0 = rows0 < 0 ? 0 : (rows0 > ROWS ? ROWS : rows0);
    int rows1 = n - (int)rb1; rows1 = rows1 < 0 ? 0 : (rows1 > ROWS ? ROWS : rows1);

    // ---- issue ALL global loads upfront (T14 issue-early) ----
    float4 p00 = make_float4(0, 0, 0, 0), p01 = p00, p02 = p00;
    float4 p10 = p00, p11 = p00, p12 = p00;
    float t0f = 0.f, t1f = 0.f;
    int4 bi0 = make_int4(0, 0, 0, 0), bi1 = bi0;
    {
        const float4* src0 = reinterpret_cast<const float4*>(v + rb0 * 3);
        int f40 = (rows0 * 3) >> 2;
        if (tid < f40)       p00 = src0[tid];
        if (tid + 256 < f40) p01 = src0[tid + 256];
        if (tid + 512 < f40) p02 = src0[tid + 512];
        int tf0 = (rows0 * 3) & 3;
        if (tf0 && tid < tf0) t0f = v[rb0 * 3 + (((size_t)f40) << 2) + tid];
    }
    if (rows1 > 0) {
        const float4* src1 = reinterpret_cast<const float4*>(v + rb1 * 3);
        int f41 = (rows1 * 3) >> 2;
        if (tid < f41)       p10 = src1[tid];
        if (tid + 256 < f41) p11 = src1[tid + 256];
        if (tid + 512 < f41) p12 = src1[tid + 512];
        int tf1 = (rows1 * 3) & 3;
        if (tf1 && tid < tf1) t1f = v[rb1 * 3 + (((size_t)f41) << 2) + tid];
    }
    if (tid < (rows0 >> 2)) {
        if (HAS_BATCH) bi0 = *(reinterpret_cast<const int4*>(batch + rb0) + tid);
        else { int b = (int)rb0 + 4 * tid; bi0 = make_int4(b, b + 1, b + 2, b + 3); }
    }
    if (rows1 > 0 && tid < (rows1 >> 2)) {
        if (HAS_BATCH) bi1 = *(reinterpret_cast<const int4*>(batch + rb1) + tid);
        else { int b = (int)rb1 + 4 * tid; bi1 = make_int4(b, b + 1, b + 2, b + 3); }
    }

    // ---- stage tile 0 ----
    {
        float4* b4 = reinterpret_cast<float4*>(buf[0]);
        int f40 = (rows0 * 3) >> 2;
        if (tid < f40)       b4[tid]       = p00;
        if (tid + 256 < f40) b4[tid + 256] = p01;
        if (tid + 512 < f40) b4[tid + 512] = p02;
        int tf0 = (rows0 * 3) & 3;
        if (tf0 && tid < tf0) buf[0][(f40 << 2) + tid] = t0f;
    }
    __syncthreads();

    rotate_tile<HAS_BATCH>(buf[0], bi0, R, batch, rb0, rows0, tid);
    __syncthreads();

    // ---- stage tile 1 into the other buffer, then store tile 0 ----
    if (rows1 > 0) {
        float4* b4 = reinterpret_cast<float4*>(buf[1]);
        int f41 = (rows1 * 3) >> 2;
        if (tid < f41)       b4[tid]       = p10;
        if (tid + 256 < f41) b4[tid + 256] = p11;
        if (tid + 512 < f41) b4[tid + 512] = p12;
        int tf1 = (rows1 * 3) & 3;
        if (tf1 && tid < tf1) buf[1][(f41 << 2) + tid] = t1f;
    }
    store_tile_nt(buf[0], out, rb0, rows0, tid);

    if (rows1 > 0) {
        __syncthreads();
        rotate_tile<HAS_BATCH>(buf[1], bi1, R, batch, rb1, rows1, tid);
        __syncthreads();
        store_tile_nt(buf[1], out, rb1, rows1, tid);
    }
}

extern "C" void kernel_launch(void* const* d_in, const int* in_sizes, int n_in,
                              void* d_out, int out_size, void* d_ws, size_t ws_size,
                              hipStream_t stream) {
    const float* x          = (const float*)d_in[0];
    const float* edge_attr  = (const float*)d_in[1];
    const float* y          = (const float*)d_in[2];
    const int*   node_batch = (const int*)d_in[3];
    const int*   edge_batch = (const int*)d_in[4];
    const float* axis       = (const float*)d_in[5];
    const float* angle      = (const float*)d_in[6];
    const float* apply_rand = (const float*)d_in[7];

    const int N = in_sizes[3];
    const int E = in_sizes[4];
    const int G = in_sizes[6];

    float* R = (float*)d_ws;        // G*12 floats = 384 KB
    float* x_out = (float*)d_out;
    float* e_out = x_out + 3 * (size_t)N;
    float* y_out = e_out + 3 * (size_t)E;

    compute_R_kernel<<<(G + BLK - 1) / BLK, BLK, 0, stream>>>(
        axis, angle, apply_rand, R, G);

    // two tiles per block
    int nbE = (int)(((size_t)E + 2 * ROWS - 1) / (2 * ROWS));
    int nbN = (int)(((size_t)N + 2 * ROWS - 1) / (2 * ROWS));
    int nbG = (int)(((size_t)G + 2 * ROWS - 1) / (2 * ROWS));

    apply_rot_lds2<true><<<nbE, BLK, 0, stream>>>(edge_attr, edge_batch, R, e_out, E);
    apply_rot_lds2<true><<<nbN, BLK, 0, stream>>>(x, node_batch, R, x_out, N);
    apply_rot_lds2<false><<<nbG, BLK, 0, stream>>>(y, nullptr, R, y_out, G);
}